// Round 4
// baseline (286.367 us; speedup 1.0000x reference)
//
#include <hip/hip_runtime.h>

// Problem constants: B=4, L=1024, D=512, N=16, OUT=512, NL=2
#define BQ 4
#define LQ 1024
#define DQ 512
#define NQ 16
#define MQ (BQ*LQ)      // 4096 rows (b,l flattened)
#define CHUNK 32
#define NCH (LQ/CHUNK)  // 32 chunks
#define KQ 512          // GEMM K (== D)
#define NFUSE 576       // 512 dt + 16 B + 16 C + 32 pad

typedef __bf16  bf16x8  __attribute__((ext_vector_type(8)));
typedef float   floatx4 __attribute__((ext_vector_type(4)));

__device__ __forceinline__ float softplus_f(float x) {
    return (x > 20.0f) ? x : log1pf(__expf(x));
}

// round-to-nearest-even fp32 -> bf16 (as ushort)
__device__ __forceinline__ unsigned short f2b(float f) {
    union { float f; unsigned u; } x; x.f = f;
    unsigned r = x.u + 0x7fffu + ((x.u >> 16) & 1u);
    return (unsigned short)(r >> 16);
}
__device__ __forceinline__ float b2f(unsigned short u) {
    union { unsigned u; float f; } x; x.u = (unsigned)u << 16;
    return x.f;
}

// ===========================================================================
// Flat MFMA GEMM core: one wave per block, 64x64 wave tile, fragments loaded
// DIRECTLY global->VGPR (16 contiguous bytes per lane = the exact A/B-operand
// fragment of mfma_f32_16x16x32_bf16). No LDS, no barriers; latency hidden by
// occupancy (~120 VGPR -> 4 waves/SIMD). Operands are L2-resident (A 4 MB,
// W 0.6 MB).
// ===========================================================================
__device__ __forceinline__ void gemm_wave_core(
    const unsigned short* __restrict__ Abf,   // [M][512]
    const unsigned short* __restrict__ Wt,    // [N][512] (transposed weights)
    int bm, int bn, int lane, floatx4 acc[4][4])
{
    const unsigned short* arow = Abf + (size_t)(bm + (lane & 15)) * KQ + ((lane >> 4) * 8);
    const unsigned short* brow = Wt  + (size_t)(bn + (lane & 15)) * KQ + ((lane >> 4) * 8);
    #pragma unroll 2
    for (int k0 = 0; k0 < KQ; k0 += 32) {
        bf16x8 af[4], bf[4];
        #pragma unroll
        for (int mt = 0; mt < 4; ++mt)
            af[mt] = *(const bf16x8*)(arow + (size_t)mt * 16 * KQ + k0);
        #pragma unroll
        for (int nt = 0; nt < 4; ++nt)
            bf[nt] = *(const bf16x8*)(brow + (size_t)nt * 16 * KQ + k0);
        #pragma unroll
        for (int mt = 0; mt < 4; ++mt)
            #pragma unroll
            for (int nt = 0; nt < 4; ++nt)
                acc[mt][nt] = __builtin_amdgcn_mfma_f32_16x16x32_bf16(
                    af[mt], bf[nt], acc[mt][nt], 0, 0, 0);
    }
}

// ---------------------------------------------------------------------------
// Plain GEMM: out = A@Wt^T + bias. F32OUT: write fp32 Cf, else bf16 Cb.
// ---------------------------------------------------------------------------
template<bool F32OUT>
__global__ __launch_bounds__(64) void gemm_flat(
    const unsigned short* __restrict__ Abf,
    const unsigned short* __restrict__ Wt,
    const float* __restrict__ bias,
    float* __restrict__ Cf, unsigned short* __restrict__ Cb, int N)
{
    const int lane = threadIdx.x;
    const int bm = blockIdx.x * 64, bn = blockIdx.y * 64;
    floatx4 acc[4][4];
    #pragma unroll
    for (int i = 0; i < 4; ++i)
        #pragma unroll
        for (int j = 0; j < 4; ++j) acc[i][j] = (floatx4){0.f,0.f,0.f,0.f};
    gemm_wave_core(Abf, Wt, bm, bn, lane, acc);

    const int col0 = lane & 15, rq = lane >> 4;
    #pragma unroll
    for (int nt = 0; nt < 4; ++nt) {
        int n = bn + nt * 16 + col0;
        float bv = bias[n];
        #pragma unroll
        for (int mt = 0; mt < 4; ++mt) {
            #pragma unroll
            for (int r = 0; r < 4; ++r) {
                int m = bm + mt * 16 + rq * 4 + r;
                float v = acc[mt][nt][r] + bv;
                if (F32OUT) Cf[(size_t)m * N + n] = v;
                else        Cb[(size_t)m * N + n] = f2b(v);
            }
        }
    }
}

// ---------------------------------------------------------------------------
// Fused dt/B/C GEMM. Wt rows: 0-511 Wdt^T, 512-527 WB^T, 528-543 WC^T,
// 544-575 zero pad. dt written as bf16 (scan reads bf16 now).
// ---------------------------------------------------------------------------
__global__ __launch_bounds__(64) void gemm_fused(
    const unsigned short* __restrict__ Abf,
    const unsigned short* __restrict__ Wt,
    const float* __restrict__ bdt, const float* __restrict__ bB,
    const float* __restrict__ bC,
    unsigned short* __restrict__ dtb, float* __restrict__ Bm, float* __restrict__ Cm)
{
    const int lane = threadIdx.x;
    const int bm = blockIdx.x * 64, bn = blockIdx.y * 64;
    floatx4 acc[4][4];
    #pragma unroll
    for (int i = 0; i < 4; ++i)
        #pragma unroll
        for (int j = 0; j < 4; ++j) acc[i][j] = (floatx4){0.f,0.f,0.f,0.f};
    gemm_wave_core(Abf, Wt, bm, bn, lane, acc);

    const int col0 = lane & 15, rq = lane >> 4;
    #pragma unroll
    for (int nt = 0; nt < 4; ++nt) {
        int nb = bn + nt * 16;     // tile-uniform region selector
        int n  = nb + col0;
        if (nb < 512) {
            float bv = bdt[n];
            #pragma unroll
            for (int mt = 0; mt < 4; ++mt)
                #pragma unroll
                for (int r = 0; r < 4; ++r) {
                    int m = bm + mt * 16 + rq * 4 + r;
                    dtb[(size_t)m * DQ + n] = f2b(softplus_f(acc[mt][nt][r] + bv));
                }
        } else if (nb < 528) {
            float bv = bB[n - 512];
            #pragma unroll
            for (int mt = 0; mt < 4; ++mt)
                #pragma unroll
                for (int r = 0; r < 4; ++r) {
                    int m = bm + mt * 16 + rq * 4 + r;
                    Bm[(size_t)m * NQ + (n - 512)] = acc[mt][nt][r] + bv;
                }
        } else if (nb < 544) {
            float bv = bC[n - 528];
            #pragma unroll
            for (int mt = 0; mt < 4; ++mt)
                #pragma unroll
                for (int r = 0; r < 4; ++r) {
                    int m = bm + mt * 16 + rq * 4 + r;
                    Cm[(size_t)m * NQ + (n - 528)] = acc[mt][nt][r] + bv;
                }
        }
    }
}

// ---------------------------------------------------------------------------
// fp32 -> bf16 cast (4 elems/thread)
// ---------------------------------------------------------------------------
__global__ __launch_bounds__(256) void cast_bf16_kernel(
    const float* __restrict__ in, unsigned short* __restrict__ out)
{
    size_t i = ((size_t)blockIdx.x * 256 + threadIdx.x) * 4;
    float4 v = *(const float4*)(in + i);
    ushort4 o;
    o.x = f2b(v.x); o.y = f2b(v.y); o.z = f2b(v.z); o.w = f2b(v.w);
    *(ushort4*)(out + i) = o;
}

// ---------------------------------------------------------------------------
// All weight transposes in one launch: z selects (src fp32 [512][512],
// dst bf16 [512][512] transposed). block (32,8), grid (16,16,5).
// ---------------------------------------------------------------------------
__global__ __launch_bounds__(256) void transpose_all(
    const float* __restrict__ Wdt, const float* __restrict__ Wlin,
    const float* __restrict__ Wdec,
    unsigned short* __restrict__ Wf, unsigned short* __restrict__ Wt_lin,
    unsigned short* __restrict__ Wt_dec)
{
    const float* src; unsigned short* dst;
    switch (blockIdx.z) {
        case 0:  src = Wdt;                   dst = Wf;                      break;
        case 1:  src = Wdt + (size_t)KQ*KQ;   dst = Wf + (size_t)NFUSE*KQ;   break;
        case 2:  src = Wlin;                  dst = Wt_lin;                  break;
        case 3:  src = Wlin + (size_t)KQ*KQ;  dst = Wt_lin + (size_t)KQ*KQ;  break;
        default: src = Wdec;                  dst = Wt_dec;                  break;
    }
    __shared__ float tile[32][33];
    int bx = blockIdx.x * 32, by = blockIdx.y * 32;
    int tx = threadIdx.x, ty = threadIdx.y;
    #pragma unroll
    for (int i = 0; i < 32; i += 8)
        tile[ty + i][tx] = src[(size_t)(bx + ty + i) * KQ + by + tx];
    __syncthreads();
    #pragma unroll
    for (int i = 0; i < 32; i += 8)
        dst[(size_t)(by + ty + i) * KQ + bx + tx] = f2b(tile[tx][ty + i]);
}

// ---------------------------------------------------------------------------
// pack WB/WC transposed (bf16) into rows 512..575 of the fused weight matrix
// (rows 544..575 zeroed). grid (64, NL).
// ---------------------------------------------------------------------------
__global__ __launch_bounds__(256) void pack_bc_kernel(
    const float* __restrict__ WB, const float* __restrict__ WC,
    unsigned short* __restrict__ Wf)
{
    int r = blockIdx.x;            // 0..63
    int layer = blockIdx.y;
    unsigned short* dst = Wf + (size_t)layer * NFUSE * KQ + (size_t)(512 + r) * KQ;
    const float* src = nullptr;
    int n = 0;
    if (r < 16)      { src = WB + (size_t)layer * DQ * NQ; n = r; }
    else if (r < 32) { src = WC + (size_t)layer * DQ * NQ; n = r - 16; }
    for (int k = threadIdx.x; k < KQ; k += 256)
        dst[k] = src ? f2b(src[(size_t)k * NQ + n]) : (unsigned short)0;
}

// ---------------------------------------------------------------------------
// Scan phase 1: per (b,d,chunk) cumulative a-product + local h (zero-init).
// dt, y now bf16.
// ---------------------------------------------------------------------------
__global__ __launch_bounds__(256) void scan_phase1(
    const unsigned short* __restrict__ dt, const unsigned short* __restrict__ y,
    const float* __restrict__ Bm, const float* __restrict__ A,
    float* __restrict__ ap, float* __restrict__ hf)
{
    int idx  = blockIdx.x;
    int dblk = idx & 1;
    int c    = (idx >> 1) & (NCH - 1);
    int b    = idx >> 6;
    int d    = dblk * 256 + threadIdx.x;

    float Ad[NQ];
    const float* Aptr = A + (size_t)d * NQ;
    #pragma unroll
    for (int n = 0; n < NQ; ++n) Ad[n] = Aptr[n];

    float h[NQ], prod[NQ];
    #pragma unroll
    for (int n = 0; n < NQ; ++n) { h[n] = 0.f; prod[n] = 1.f; }

    int t0 = c * CHUNK;
    const unsigned short* dtp = dt + ((size_t)b*LQ + t0) * DQ + d;
    const unsigned short* yp  = y  + ((size_t)b*LQ + t0) * DQ + d;
    const float* bp  = Bm + ((size_t)b*LQ + t0) * NQ;

    #pragma unroll 4
    for (int t = 0; t < CHUNK; ++t) {
        float dtv = b2f(dtp[(size_t)t * DQ]);
        float yv  = b2f(yp[(size_t)t * DQ]);
        float dty = dtv * yv;
        #pragma unroll
        for (int n = 0; n < NQ; ++n) {
            float a = __expf(dtv * Ad[n]);
            prod[n] *= a;
            h[n] = fmaf(a, h[n], dty * bp[t*NQ + n]);
        }
    }
    size_t base = ((size_t)(b*NCH + c) * DQ + d) * NQ;
    #pragma unroll
    for (int n = 0; n < NQ; n += 4) {
        *(float4*)(ap + base + n) = make_float4(prod[n], prod[n+1], prod[n+2], prod[n+3]);
        *(float4*)(hf + base + n) = make_float4(h[n], h[n+1], h[n+2], h[n+3]);
    }
}

// ---------------------------------------------------------------------------
// Scan phase 2: sequential scan over NCH chunk summaries; h_init in-place.
// ---------------------------------------------------------------------------
__global__ __launch_bounds__(256) void scan_phase2(
    float* ap, const float* __restrict__ hf)
{
    int g = blockIdx.x * 256 + threadIdx.x;   // B*D*N threads
    int n = g & (NQ - 1);
    int d = (g >> 4) & (DQ - 1);
    int b = g >> 13;
    float h = 0.f;
    for (int c = 0; c < NCH; ++c) {
        size_t idx = ((size_t)(b*NCH + c) * DQ + d) * NQ + n;
        float a = ap[idx];
        float f = hf[idx];
        ap[idx] = h;
        h = fmaf(a, h, f);
    }
}

// ---------------------------------------------------------------------------
// Scan phase 3: recompute local scan with h_init, emit bf16
// yact = relu(sum_n h*Cm + Dskip*y)
// ---------------------------------------------------------------------------
__global__ __launch_bounds__(256) void scan_phase3(
    const unsigned short* __restrict__ dt, const unsigned short* __restrict__ y,
    const float* __restrict__ Bm, const float* __restrict__ Cm,
    const float* __restrict__ A, const float* __restrict__ Dsk,
    const float* __restrict__ hi, unsigned short* __restrict__ yact)
{
    int idx  = blockIdx.x;
    int dblk = idx & 1;
    int c    = (idx >> 1) & (NCH - 1);
    int b    = idx >> 6;
    int d    = dblk * 256 + threadIdx.x;

    float Ad[NQ];
    const float* Aptr = A + (size_t)d * NQ;
    #pragma unroll
    for (int n = 0; n < NQ; ++n) Ad[n] = Aptr[n];

    float h[NQ];
    size_t base = ((size_t)(b*NCH + c) * DQ + d) * NQ;
    #pragma unroll
    for (int n = 0; n < NQ; n += 4) {
        float4 v = *(const float4*)(hi + base + n);
        h[n] = v.x; h[n+1] = v.y; h[n+2] = v.z; h[n+3] = v.w;
    }
    float dskip = Dsk[d];

    int t0 = c * CHUNK;
    const unsigned short* dtp = dt + ((size_t)b*LQ + t0) * DQ + d;
    const unsigned short* yp  = y  + ((size_t)b*LQ + t0) * DQ + d;
    const float* bp  = Bm + ((size_t)b*LQ + t0) * NQ;
    const float* cp  = Cm + ((size_t)b*LQ + t0) * NQ;
    unsigned short* op = yact + ((size_t)b*LQ + t0) * DQ + d;

    #pragma unroll 4
    for (int t = 0; t < CHUNK; ++t) {
        float dtv = b2f(dtp[(size_t)t * DQ]);
        float yv  = b2f(yp[(size_t)t * DQ]);
        float dty = dtv * yv;
        float acc = 0.f;
        #pragma unroll
        for (int n = 0; n < NQ; ++n) {
            float a = __expf(dtv * Ad[n]);
            h[n] = fmaf(a, h[n], dty * bp[t*NQ + n]);
            acc = fmaf(h[n], cp[t*NQ + n], acc);
        }
        float v = acc + dskip * yv;
        op[(size_t)t * DQ] = f2b(fmaxf(v, 0.f));
    }
}

// ---------------------------------------------------------------------------
extern "C" void kernel_launch(void* const* d_in, const int* in_sizes, int n_in,
                              void* d_out, int out_size, void* d_ws, size_t ws_size,
                              hipStream_t stream)
{
    const float* x    = (const float*)d_in[0];
    const float* A    = (const float*)d_in[1];
    const float* Dsk  = (const float*)d_in[2];
    const float* WB   = (const float*)d_in[3];
    const float* bB   = (const float*)d_in[4];
    const float* WC   = (const float*)d_in[5];
    const float* bC   = (const float*)d_in[6];
    const float* Wdt  = (const float*)d_in[7];
    const float* bdt  = (const float*)d_in[8];
    const float* Wlin = (const float*)d_in[9];
    const float* blin = (const float*)d_in[10];
    const float* Wdec = (const float*)d_in[11];
    const float* bdec = (const float*)d_in[12];
    float* out = (float*)d_out;

    // workspace layout
    char* cur = (char*)d_ws;
    float* Bm   = (float*)cur;           cur += (size_t)MQ*NQ*4;          // 256 KB
    float* Cm   = (float*)cur;           cur += (size_t)MQ*NQ*4;          // 256 KB
    float* ap   = (float*)cur;           cur += (size_t)BQ*NCH*DQ*NQ*4;   // 4 MB
    float* hf   = (float*)cur;           cur += (size_t)BQ*NCH*DQ*NQ*4;   // 4 MB
    unsigned short* y16    = (unsigned short*)cur; cur += (size_t)MQ*DQ*2;   // 4 MB
    unsigned short* dtb16  = (unsigned short*)cur; cur += (size_t)MQ*DQ*2;   // 4 MB
    unsigned short* yact16 = (unsigned short*)cur; cur += (size_t)MQ*DQ*2;   // 4 MB
    unsigned short* Wf     = (unsigned short*)cur; cur += (size_t)2*NFUSE*KQ*2; // 1.125 MB
    unsigned short* Wt_lin = (unsigned short*)cur; cur += (size_t)2*KQ*KQ*2;   // 1 MB
    unsigned short* Wt_dec = (unsigned short*)cur; cur += (size_t)KQ*KQ*2;     // 0.5 MB

    dim3 blk(256);
    dim3 blk64(64);
    dim3 blkT(32, 8);

    // weight prep (every call; inputs restored before each timed launch)
    transpose_all<<<dim3(16,16,5), blkT, 0, stream>>>(
        Wdt, Wlin, Wdec, Wf, Wt_lin, Wt_dec);
    pack_bc_kernel<<<dim3(64, 2), blk, 0, stream>>>(WB, WC, Wf);
    cast_bf16_kernel<<<dim3(MQ*DQ/1024), blk, 0, stream>>>(x, y16);

    dim3 gFused(MQ/64, NFUSE/64);   // 64 x 9
    dim3 gOut(MQ/64, DQ/64);        // 64 x 8
    for (int layer = 0; layer < 2; ++layer) {
        // dt (softplus, ->bf16) + Bm + Cm in one flat MFMA GEMM
        gemm_fused<<<gFused, blk64, 0, stream>>>(
            y16, Wf + (size_t)layer*NFUSE*KQ,
            bdt + (size_t)layer*DQ, bB + (size_t)layer*NQ, bC + (size_t)layer*NQ,
            dtb16, Bm, Cm);
        // chunked scan (all bf16 activations)
        scan_phase1<<<dim3(BQ*NCH*(DQ/256)), blk, 0, stream>>>(
            dtb16, y16, Bm, A + (size_t)layer*DQ*NQ, ap, hf);
        scan_phase2<<<dim3(BQ*DQ*NQ/256), blk, 0, stream>>>(ap, hf);
        scan_phase3<<<dim3(BQ*NCH*(DQ/256)), blk, 0, stream>>>(
            dtb16, y16, Bm, Cm, A + (size_t)layer*DQ*NQ, Dsk + (size_t)layer*DQ,
            ap, yact16);
        // y = yact @ Wlin + blin  (bf16 out, overwrites y16)
        gemm_flat<false><<<gOut, blk64, 0, stream>>>(
            yact16, Wt_lin + (size_t)layer*KQ*KQ, blin + (size_t)layer*DQ,
            (float*)nullptr, y16, DQ);
    }
    // decoder (fp32 out)
    gemm_flat<true><<<gOut, blk64, 0, stream>>>(
        y16, Wt_dec, bdec, out, (unsigned short*)nullptr, DQ);
}

// Round 5
// 270.524 us; speedup vs baseline: 1.0586x; 1.0586x over previous
//
#include <hip/hip_runtime.h>

// Problem constants: B=4, L=1024, D=512, N=16, OUT=512, NL=2
#define BQ 4
#define LQ 1024
#define DQ 512
#define NQ 16
#define MQ (BQ*LQ)      // 4096 rows (b,l flattened)
#define CHUNK 32
#define NCH (LQ/CHUNK)  // 32 chunks
#define KQ 512          // GEMM K (== D)
#define NFUSE 576       // 512 dt + 16 B + 16 C + 32 pad
#define APITCH 520      // LDS row pitch (elems): 1040 B, 16B-aligned, bank-skewed

typedef __bf16  bf16x8  __attribute__((ext_vector_type(8)));
typedef float   floatx4 __attribute__((ext_vector_type(4)));

__device__ __forceinline__ float softplus_f(float x) {
    return (x > 20.0f) ? x : log1pf(__expf(x));
}

// round-to-nearest-even fp32 -> bf16 (as ushort)
__device__ __forceinline__ unsigned short f2b(float f) {
    union { float f; unsigned u; } x; x.f = f;
    unsigned r = x.u + 0x7fffu + ((x.u >> 16) & 1u);
    return (unsigned short)(r >> 16);
}
__device__ __forceinline__ float b2f(unsigned short u) {
    union { unsigned u; float f; } x; x.u = (unsigned)u << 16;
    return x.f;
}

__device__ __forceinline__ void load_lds16(const void* g, void* l) {
    __builtin_amdgcn_global_load_lds(
        (const __attribute__((address_space(1))) unsigned int*)g,
        (__attribute__((address_space(3))) unsigned int*)l,
        16, 0, 0);
}

// ===========================================================================
// A-resident GEMM: block stages a 32-row x 512-K A-tile into LDS ONCE
// (one barrier per block), then does barrier-free K-sweeps over 32-col
// weight tiles with B-fragments streamed global->VGPR (weights are L2-hot).
// 4 waves; wave tile 32x32 (2x2 of 16x16x32 MFMA). grid (MQ/32, 2);
// wave handles tiles {blockIdx.y*4 + wave, +8, ...}.
// ===========================================================================
__device__ __forceinline__ void stage_A(
    const unsigned short* __restrict__ Abf, int bm,
    unsigned short* As, int wave, int lane)
{
    #pragma unroll
    for (int r = 0; r < 8; ++r) {
        int row = wave * 8 + r;
        load_lds16(Abf + (size_t)(bm + row) * KQ + lane * 8, As + row * APITCH);
    }
    __syncthreads();   // single full drain per block
}

__device__ __forceinline__ void ksweep(
    const unsigned short* As, const unsigned short* __restrict__ Wt,
    int tile, int lane, floatx4 acc[2][2])
{
    const int col = lane & 15, kg = (lane >> 4) * 8;
    const unsigned short* wp = Wt + (size_t)(tile * 32 + col) * KQ + kg;
    const unsigned short* ap = As + col * APITCH + kg;
    #pragma unroll 4
    for (int k0 = 0; k0 < KQ; k0 += 32) {
        bf16x8 af0 = *(const bf16x8*)(ap + k0);
        bf16x8 af1 = *(const bf16x8*)(ap + 16 * APITCH + k0);
        bf16x8 bf0 = *(const bf16x8*)(wp + k0);
        bf16x8 bf1 = *(const bf16x8*)(wp + (size_t)16 * KQ + k0);
        acc[0][0] = __builtin_amdgcn_mfma_f32_16x16x32_bf16(af0, bf0, acc[0][0], 0,0,0);
        acc[1][0] = __builtin_amdgcn_mfma_f32_16x16x32_bf16(af1, bf0, acc[1][0], 0,0,0);
        acc[0][1] = __builtin_amdgcn_mfma_f32_16x16x32_bf16(af0, bf1, acc[0][1], 0,0,0);
        acc[1][1] = __builtin_amdgcn_mfma_f32_16x16x32_bf16(af1, bf1, acc[1][1], 0,0,0);
    }
}

// ---------------------------------------------------------------------------
// Plain GEMM: out = A@Wt^T + bias. ntiles = N/32. F32OUT -> Cf else bf16 Cb.
// ---------------------------------------------------------------------------
template<bool F32OUT>
__global__ __launch_bounds__(256) void gemm_a32(
    const unsigned short* __restrict__ Abf,
    const unsigned short* __restrict__ Wt,
    const float* __restrict__ bias,
    float* __restrict__ Cf, unsigned short* __restrict__ Cb,
    int ntiles, int N)
{
    __shared__ __align__(16) unsigned short As[32 * APITCH];  // 33 KB
    const int lane = threadIdx.x & 63, wave = threadIdx.x >> 6;
    const int bm = blockIdx.x * 32;
    stage_A(Abf, bm, As, wave, lane);

    const int col0 = lane & 15, rq = lane >> 4;
    for (int tile = blockIdx.y * 4 + wave; tile < ntiles; tile += 8) {
        floatx4 acc[2][2];
        #pragma unroll
        for (int i = 0; i < 2; ++i)
            #pragma unroll
            for (int j = 0; j < 2; ++j) acc[i][j] = (floatx4){0.f,0.f,0.f,0.f};
        ksweep(As, Wt, tile, lane, acc);
        #pragma unroll
        for (int nt = 0; nt < 2; ++nt) {
            int n = tile * 32 + nt * 16 + col0;
            float bv = bias[n];
            #pragma unroll
            for (int mt = 0; mt < 2; ++mt)
                #pragma unroll
                for (int r = 0; r < 4; ++r) {
                    int m = bm + mt * 16 + rq * 4 + r;
                    float v = acc[mt][nt][r] + bv;
                    if (F32OUT) Cf[(size_t)m * N + n] = v;
                    else        Cb[(size_t)m * N + n] = f2b(v);
                }
        }
    }
}

// ---------------------------------------------------------------------------
// Fused dt/B/C GEMM: Wt rows 0-511 Wdt^T, 512-527 WB^T, 528-543 WC^T,
// 544-575 zero. ntiles = 18 (32-wide). Epilogue routes per 16-col region.
// ---------------------------------------------------------------------------
__global__ __launch_bounds__(256) void gemm_a32_fused(
    const unsigned short* __restrict__ Abf,
    const unsigned short* __restrict__ Wt,
    const float* __restrict__ bdt, const float* __restrict__ bB,
    const float* __restrict__ bC,
    unsigned short* __restrict__ dtb, float* __restrict__ Bm, float* __restrict__ Cm)
{
    __shared__ __align__(16) unsigned short As[32 * APITCH];  // 33 KB
    const int lane = threadIdx.x & 63, wave = threadIdx.x >> 6;
    const int bm = blockIdx.x * 32;
    stage_A(Abf, bm, As, wave, lane);

    const int col0 = lane & 15, rq = lane >> 4;
    for (int tile = blockIdx.y * 4 + wave; tile < NFUSE/32; tile += 8) {
        floatx4 acc[2][2];
        #pragma unroll
        for (int i = 0; i < 2; ++i)
            #pragma unroll
            for (int j = 0; j < 2; ++j) acc[i][j] = (floatx4){0.f,0.f,0.f,0.f};
        ksweep(As, Wt, tile, lane, acc);
        #pragma unroll
        for (int nt = 0; nt < 2; ++nt) {
            int nb = tile * 32 + nt * 16;   // region selector (uniform per frag)
            int n  = nb + col0;
            if (nb < 512) {
                float bv = bdt[n];
                #pragma unroll
                for (int mt = 0; mt < 2; ++mt)
                    #pragma unroll
                    for (int r = 0; r < 4; ++r) {
                        int m = bm + mt * 16 + rq * 4 + r;
                        dtb[(size_t)m * DQ + n] = f2b(softplus_f(acc[mt][nt][r] + bv));
                    }
            } else if (nb < 528) {
                float bv = bB[n - 512];
                #pragma unroll
                for (int mt = 0; mt < 2; ++mt)
                    #pragma unroll
                    for (int r = 0; r < 4; ++r) {
                        int m = bm + mt * 16 + rq * 4 + r;
                        Bm[(size_t)m * NQ + (n - 512)] = acc[mt][nt][r] + bv;
                    }
            } else if (nb < 544) {
                float bv = bC[n - 528];
                #pragma unroll
                for (int mt = 0; mt < 2; ++mt)
                    #pragma unroll
                    for (int r = 0; r < 4; ++r) {
                        int m = bm + mt * 16 + rq * 4 + r;
                        Cm[(size_t)m * NQ + (n - 528)] = acc[mt][nt][r] + bv;
                    }
            }
            // nb >= 544: zero pad, skip
        }
    }
}

// ---------------------------------------------------------------------------
// fp32 -> bf16 cast (4 elems/thread)
// ---------------------------------------------------------------------------
__global__ __launch_bounds__(256) void cast_bf16_kernel(
    const float* __restrict__ in, unsigned short* __restrict__ out)
{
    size_t i = ((size_t)blockIdx.x * 256 + threadIdx.x) * 4;
    float4 v = *(const float4*)(in + i);
    ushort4 o;
    o.x = f2b(v.x); o.y = f2b(v.y); o.z = f2b(v.z); o.w = f2b(v.w);
    *(ushort4*)(out + i) = o;
}

// ---------------------------------------------------------------------------
// All weight transposes in one launch. block (32,8), grid (16,16,5).
// ---------------------------------------------------------------------------
__global__ __launch_bounds__(256) void transpose_all(
    const float* __restrict__ Wdt, const float* __restrict__ Wlin,
    const float* __restrict__ Wdec,
    unsigned short* __restrict__ Wf, unsigned short* __restrict__ Wt_lin,
    unsigned short* __restrict__ Wt_dec)
{
    const float* src; unsigned short* dst;
    switch (blockIdx.z) {
        case 0:  src = Wdt;                   dst = Wf;                      break;
        case 1:  src = Wdt + (size_t)KQ*KQ;   dst = Wf + (size_t)NFUSE*KQ;   break;
        case 2:  src = Wlin;                  dst = Wt_lin;                  break;
        case 3:  src = Wlin + (size_t)KQ*KQ;  dst = Wt_lin + (size_t)KQ*KQ;  break;
        default: src = Wdec;                  dst = Wt_dec;                  break;
    }
    __shared__ float tile[32][33];
    int bx = blockIdx.x * 32, by = blockIdx.y * 32;
    int tx = threadIdx.x, ty = threadIdx.y;
    #pragma unroll
    for (int i = 0; i < 32; i += 8)
        tile[ty + i][tx] = src[(size_t)(bx + ty + i) * KQ + by + tx];
    __syncthreads();
    #pragma unroll
    for (int i = 0; i < 32; i += 8)
        dst[(size_t)(by + ty + i) * KQ + bx + tx] = f2b(tile[tx][ty + i]);
}

// ---------------------------------------------------------------------------
// pack WB/WC transposed (bf16) into rows 512..575 of the fused weight matrix
// (rows 544..575 zeroed). grid (64, NL).
// ---------------------------------------------------------------------------
__global__ __launch_bounds__(256) void pack_bc_kernel(
    const float* __restrict__ WB, const float* __restrict__ WC,
    unsigned short* __restrict__ Wf)
{
    int r = blockIdx.x;            // 0..63
    int layer = blockIdx.y;
    unsigned short* dst = Wf + (size_t)layer * NFUSE * KQ + (size_t)(512 + r) * KQ;
    const float* src = nullptr;
    int n = 0;
    if (r < 16)      { src = WB + (size_t)layer * DQ * NQ; n = r; }
    else if (r < 32) { src = WC + (size_t)layer * DQ * NQ; n = r - 16; }
    for (int k = threadIdx.x; k < KQ; k += 256)
        dst[k] = src ? f2b(src[(size_t)k * NQ + n]) : (unsigned short)0;
}

// ---------------------------------------------------------------------------
// Scan phase 1: per (b,d,chunk) cumulative a-product + local h (zero-init).
// ---------------------------------------------------------------------------
__global__ __launch_bounds__(256) void scan_phase1(
    const unsigned short* __restrict__ dt, const unsigned short* __restrict__ y,
    const float* __restrict__ Bm, const float* __restrict__ A,
    float* __restrict__ ap, float* __restrict__ hf)
{
    int idx  = blockIdx.x;
    int dblk = idx & 1;
    int c    = (idx >> 1) & (NCH - 1);
    int b    = idx >> 6;
    int d    = dblk * 256 + threadIdx.x;

    float Ad[NQ];
    const float* Aptr = A + (size_t)d * NQ;
    #pragma unroll
    for (int n = 0; n < NQ; ++n) Ad[n] = Aptr[n];

    float h[NQ], prod[NQ];
    #pragma unroll
    for (int n = 0; n < NQ; ++n) { h[n] = 0.f; prod[n] = 1.f; }

    int t0 = c * CHUNK;
    const unsigned short* dtp = dt + ((size_t)b*LQ + t0) * DQ + d;
    const unsigned short* yp  = y  + ((size_t)b*LQ + t0) * DQ + d;
    const float* bp  = Bm + ((size_t)b*LQ + t0) * NQ;

    #pragma unroll 4
    for (int t = 0; t < CHUNK; ++t) {
        float dtv = b2f(dtp[(size_t)t * DQ]);
        float yv  = b2f(yp[(size_t)t * DQ]);
        float dty = dtv * yv;
        #pragma unroll
        for (int n = 0; n < NQ; ++n) {
            float a = __expf(dtv * Ad[n]);
            prod[n] *= a;
            h[n] = fmaf(a, h[n], dty * bp[t*NQ + n]);
        }
    }
    size_t base = ((size_t)(b*NCH + c) * DQ + d) * NQ;
    #pragma unroll
    for (int n = 0; n < NQ; n += 4) {
        *(float4*)(ap + base + n) = make_float4(prod[n], prod[n+1], prod[n+2], prod[n+3]);
        *(float4*)(hf + base + n) = make_float4(h[n], h[n+1], h[n+2], h[n+3]);
    }
}

// ---------------------------------------------------------------------------
// Scan phase 2: sequential scan over NCH chunk summaries; h_init in-place.
// ---------------------------------------------------------------------------
__global__ __launch_bounds__(256) void scan_phase2(
    float* ap, const float* __restrict__ hf)
{
    int g = blockIdx.x * 256 + threadIdx.x;   // B*D*N threads
    int n = g & (NQ - 1);
    int d = (g >> 4) & (DQ - 1);
    int b = g >> 13;
    float h = 0.f;
    for (int c = 0; c < NCH; ++c) {
        size_t idx = ((size_t)(b*NCH + c) * DQ + d) * NQ + n;
        float a = ap[idx];
        float f = hf[idx];
        ap[idx] = h;
        h = fmaf(a, h, f);
    }
}

// ---------------------------------------------------------------------------
// Scan phase 3: recompute local scan with h_init, emit bf16
// yact = relu(sum_n h*Cm + Dskip*y)
// ---------------------------------------------------------------------------
__global__ __launch_bounds__(256) void scan_phase3(
    const unsigned short* __restrict__ dt, const unsigned short* __restrict__ y,
    const float* __restrict__ Bm, const float* __restrict__ Cm,
    const float* __restrict__ A, const float* __restrict__ Dsk,
    const float* __restrict__ hi, unsigned short* __restrict__ yact)
{
    int idx  = blockIdx.x;
    int dblk = idx & 1;
    int c    = (idx >> 1) & (NCH - 1);
    int b    = idx >> 6;
    int d    = dblk * 256 + threadIdx.x;

    float Ad[NQ];
    const float* Aptr = A + (size_t)d * NQ;
    #pragma unroll
    for (int n = 0; n < NQ; ++n) Ad[n] = Aptr[n];

    float h[NQ];
    size_t base = ((size_t)(b*NCH + c) * DQ + d) * NQ;
    #pragma unroll
    for (int n = 0; n < NQ; n += 4) {
        float4 v = *(const float4*)(hi + base + n);
        h[n] = v.x; h[n+1] = v.y; h[n+2] = v.z; h[n+3] = v.w;
    }
    float dskip = Dsk[d];

    int t0 = c * CHUNK;
    const unsigned short* dtp = dt + ((size_t)b*LQ + t0) * DQ + d;
    const unsigned short* yp  = y  + ((size_t)b*LQ + t0) * DQ + d;
    const float* bp  = Bm + ((size_t)b*LQ + t0) * NQ;
    const float* cp  = Cm + ((size_t)b*LQ + t0) * NQ;
    unsigned short* op = yact + ((size_t)b*LQ + t0) * DQ + d;

    #pragma unroll 4
    for (int t = 0; t < CHUNK; ++t) {
        float dtv = b2f(dtp[(size_t)t * DQ]);
        float yv  = b2f(yp[(size_t)t * DQ]);
        float dty = dtv * yv;
        float acc = 0.f;
        #pragma unroll
        for (int n = 0; n < NQ; ++n) {
            float a = __expf(dtv * Ad[n]);
            h[n] = fmaf(a, h[n], dty * bp[t*NQ + n]);
            acc = fmaf(h[n], cp[t*NQ + n], acc);
        }
        float v = acc + dskip * yv;
        op[(size_t)t * DQ] = f2b(fmaxf(v, 0.f));
    }
}

// ---------------------------------------------------------------------------
extern "C" void kernel_launch(void* const* d_in, const int* in_sizes, int n_in,
                              void* d_out, int out_size, void* d_ws, size_t ws_size,
                              hipStream_t stream)
{
    const float* x    = (const float*)d_in[0];
    const float* A    = (const float*)d_in[1];
    const float* Dsk  = (const float*)d_in[2];
    const float* WB   = (const float*)d_in[3];
    const float* bB   = (const float*)d_in[4];
    const float* WC   = (const float*)d_in[5];
    const float* bC   = (const float*)d_in[6];
    const float* Wdt  = (const float*)d_in[7];
    const float* bdt  = (const float*)d_in[8];
    const float* Wlin = (const float*)d_in[9];
    const float* blin = (const float*)d_in[10];
    const float* Wdec = (const float*)d_in[11];
    const float* bdec = (const float*)d_in[12];
    float* out = (float*)d_out;

    // workspace layout
    char* cur = (char*)d_ws;
    float* Bm   = (float*)cur;           cur += (size_t)MQ*NQ*4;          // 256 KB
    float* Cm   = (float*)cur;           cur += (size_t)MQ*NQ*4;          // 256 KB
    float* ap   = (float*)cur;           cur += (size_t)BQ*NCH*DQ*NQ*4;   // 4 MB
    float* hf   = (float*)cur;           cur += (size_t)BQ*NCH*DQ*NQ*4;   // 4 MB
    unsigned short* y16    = (unsigned short*)cur; cur += (size_t)MQ*DQ*2;   // 4 MB
    unsigned short* dtb16  = (unsigned short*)cur; cur += (size_t)MQ*DQ*2;   // 4 MB
    unsigned short* yact16 = (unsigned short*)cur; cur += (size_t)MQ*DQ*2;   // 4 MB
    unsigned short* Wf     = (unsigned short*)cur; cur += (size_t)2*NFUSE*KQ*2; // 1.125 MB
    unsigned short* Wt_lin = (unsigned short*)cur; cur += (size_t)2*KQ*KQ*2;   // 1 MB
    unsigned short* Wt_dec = (unsigned short*)cur; cur += (size_t)KQ*KQ*2;     // 0.5 MB

    dim3 blk(256);
    dim3 blkT(32, 8);

    // weight prep (every call; inputs restored before each timed launch)
    transpose_all<<<dim3(16,16,5), blkT, 0, stream>>>(
        Wdt, Wlin, Wdec, Wf, Wt_lin, Wt_dec);
    pack_bc_kernel<<<dim3(64, 2), blk, 0, stream>>>(WB, WC, Wf);
    cast_bf16_kernel<<<dim3(MQ*DQ/1024), blk, 0, stream>>>(x, y16);

    dim3 gGemm(MQ/32, 2);   // 128 x 2 = 256 blocks
    for (int layer = 0; layer < 2; ++layer) {
        // dt (softplus, ->bf16) + Bm + Cm in one A-resident MFMA GEMM
        gemm_a32_fused<<<gGemm, blk, 0, stream>>>(
            y16, Wf + (size_t)layer*NFUSE*KQ,
            bdt + (size_t)layer*DQ, bB + (size_t)layer*NQ, bC + (size_t)layer*NQ,
            dtb16, Bm, Cm);
        // chunked scan (bf16 activations)
        scan_phase1<<<dim3(BQ*NCH*(DQ/256)), blk, 0, stream>>>(
            dtb16, y16, Bm, A + (size_t)layer*DQ*NQ, ap, hf);
        scan_phase2<<<dim3(BQ*DQ*NQ/256), blk, 0, stream>>>(ap, hf);
        scan_phase3<<<dim3(BQ*NCH*(DQ/256)), blk, 0, stream>>>(
            dtb16, y16, Bm, Cm, A + (size_t)layer*DQ*NQ, Dsk + (size_t)layer*DQ,
            ap, yact16);
        // y = yact @ Wlin + blin  (bf16 out, overwrites y16)
        gemm_a32<false><<<gGemm, blk, 0, stream>>>(
            yact16, Wt_lin + (size_t)layer*KQ*KQ, blin + (size_t)layer*DQ,
            (float*)nullptr, y16, DQ/32, DQ);
    }
    // decoder (fp32 out)
    gemm_a32<true><<<gGemm, blk, 0, stream>>>(
        y16, Wt_dec, bdec, out, (unsigned short*)nullptr, DQ/32, DQ);
}